// Round 3
// baseline (474.906 us; speedup 1.0000x reference)
//
#include <hip/hip_runtime.h>
#include <math.h>

#define ETA 0.1f

#define C0 1.0f
#define C1 1.0f
#define C2 0.5f
#define C3 (1.0f/6.0f)
#define C4 (1.0f/24.0f)
#define C5 (1.0f/120.0f)
#define C6 (1.0f/720.0f)
#define C7 (1.0f/5040.0f)
#define C8 (1.0f/40320.0f)
#define C9 (1.0f/362880.0f)

typedef __attribute__((ext_vector_type(8))) short short8;
typedef __attribute__((ext_vector_type(4))) float f32x4;

// fp32 staging buffer swizzle (16 float4-chunks per row, XOR by row)
__device__ __forceinline__ int swzF(int r, int cc) { return r * 64 + 4 * (cc ^ (r & 15)); }

// bf16 row-major layout (ushort units)
__device__ __forceinline__ int rmI(int r, int c) {
    return r * 64 + 8 * ((c >> 3) ^ (r & 7)) + (c & 7);
}
// bf16 col-major layout
__device__ __forceinline__ int cmI(int r, int c) {
    return c * 64 + 8 * ((r >> 3) ^ (c & 7)) + (r & 7);
}

// split fp32 -> bf16 hi (RNE) + bf16 lo (trunc of residual)
__device__ __forceinline__ void splitbf(float x, unsigned short& h, unsigned short& l) {
    unsigned u = __float_as_uint(x);
    unsigned r = u + 0x7FFFu + ((u >> 16) & 1u);
    h = (unsigned short)(r >> 16);
    float d = x - __uint_as_float(r & 0xFFFF0000u);
    l = (unsigned short)(__float_as_uint(d) >> 16);
}
__device__ __forceinline__ float bf2f(unsigned short h) {
    return __uint_as_float(((unsigned)h) << 16);
}

// 4x4 transpose across the 4-lane cluster (lane bits 0-1), 2 shfl_xor rounds.
// In: lane i (within cluster) holds v[j] = M[i][j]. Out: v[j] = M[j][i].
__device__ __forceinline__ void xpose4(float v[4], int lane) {
    float s, g;
    s = (lane & 1) ? v[0] : v[1];  g = __shfl_xor(s, 1);
    if (lane & 1) v[0] = g; else v[1] = g;
    s = (lane & 1) ? v[2] : v[3];  g = __shfl_xor(s, 1);
    if (lane & 1) v[2] = g; else v[3] = g;
    s = (lane & 2) ? v[0] : v[2];  g = __shfl_xor(s, 2);
    if (lane & 2) v[0] = g; else v[2] = g;
    s = (lane & 2) ? v[1] : v[3];  g = __shfl_xor(s, 2);
    if (lane & 2) v[1] = g; else v[3] = g;
}

// One 64x64 matmul stage, split-bf16 3 products (hh, hl, lh; ll dropped, <=2^-18).
// All LDS reads before mid-barrier -> fully in-place safe.
// t0mode: Oh/Ol <- cB*bm + cI*I (T0), ORh/ORl <- raw acc (B2, transposed in-reg).
// else:   Oh/Ol <- acc (+ cB*bm + cI*I when bmf); ORh also gets that value.
// gout non-null: final stage, fp32 straight to global, no LDS writes/barriers.
__device__ __forceinline__ void mmstage(
    const unsigned short* Ah, const unsigned short* Al,
    const unsigned short* Bh, const unsigned short* Bl,
    unsigned short* Oh, unsigned short* Ol,
    unsigned short* ORh, unsigned short* ORl,
    float* gout, long long gbase,
    const float* bmf, float cI, float cB, bool t0mode,
    int wv, int lane)
{
    const int n16 = lane & 15;
    const int q = lane >> 4;           // 0..3
    const int mrow = 16 * wv + n16;    // A-operand row for this lane

    short8 ah[2], al[2], bh[4][2], bl[4][2];
#pragma unroll
    for (int ks = 0; ks < 2; ++ks) {
        int k0 = 32 * ks + 8 * q;
        int ia = rmI(mrow, k0);
        ah[ks] = *(const short8*)(Ah + ia);
        al[ks] = *(const short8*)(Al + ia);
#pragma unroll
        for (int t4 = 0; t4 < 4; ++t4) {
            int ib = cmI(k0, 16 * t4 + n16);
            bh[t4][ks] = *(const short8*)(Bh + ib);
            bl[t4][ks] = *(const short8*)(Bl + ib);
        }
    }

    f32x4 acc[4] = {{0.f,0.f,0.f,0.f},{0.f,0.f,0.f,0.f},{0.f,0.f,0.f,0.f},{0.f,0.f,0.f,0.f}};
#pragma unroll
    for (int ks = 0; ks < 2; ++ks) {
#pragma unroll
        for (int t4 = 0; t4 < 4; ++t4)
            acc[t4] = __builtin_amdgcn_mfma_f32_16x16x32_bf16(ah[ks], bh[t4][ks], acc[t4], 0, 0, 0);
#pragma unroll
        for (int t4 = 0; t4 < 4; ++t4)
            acc[t4] = __builtin_amdgcn_mfma_f32_16x16x32_bf16(ah[ks], bl[t4][ks], acc[t4], 0, 0, 0);
#pragma unroll
        for (int t4 = 0; t4 < 4; ++t4)
            acc[t4] = __builtin_amdgcn_mfma_f32_16x16x32_bf16(al[ks], bh[t4][ks], acc[t4], 0, 0, 0);
    }

    const int rbase = 16 * wv + 4 * q;   // C/D: row = rbase+rg, col = 16*t4+n16
    float cmv[4][4];
#pragma unroll
    for (int t4 = 0; t4 < 4; ++t4) {
        const int c = 16 * t4 + n16;
#pragma unroll
        for (int rg = 0; rg < 4; ++rg) {
            float a = acc[t4][rg];
            if (bmf && !t0mode) {
                a += cB * bmf[4 * t4 + rg] + (((rbase + rg) == c) ? cI : 0.f);
                acc[t4][rg] = a;           // rm side (X0) carries the adds too
                cmv[t4][rg] = a;
            } else if (t0mode) {
                cmv[t4][rg] = cB * bmf[4 * t4 + rg] + (((rbase + rg) == c) ? cI : 0.f);
                // acc stays raw B2 for the rm side
            } else {
                cmv[t4][rg] = a;
            }
        }
    }

    if (gout) {   // final stage: fp32 straight to HBM, kernel ends after this
        float* gp = gout + gbase;
#pragma unroll
        for (int t4 = 0; t4 < 4; ++t4) {
            const int c = 16 * t4 + n16;
#pragma unroll
            for (int rg = 0; rg < 4; ++rg)
                gp[(rbase + rg) * 64 + c] = cmv[t4][rg];
        }
        return;
    }

    // ---- pre-barrier: everything into registers ----
    ushort4 cmH[4], cmL[4], rmH[4], rmL[4];
#pragma unroll
    for (int t4 = 0; t4 < 4; ++t4) {
        unsigned short h[4], l[4];
#pragma unroll
        for (int rg = 0; rg < 4; ++rg) splitbf(cmv[t4][rg], h[rg], l[rg]);
        cmH[t4] = make_ushort4(h[0], h[1], h[2], h[3]);
        cmL[t4] = make_ushort4(l[0], l[1], l[2], l[3]);
    }
    if (ORh) {
        // transpose each 4x4 block in-register: lane then holds a ROW run of 4
#pragma unroll
        for (int t4 = 0; t4 < 4; ++t4) {
            float v[4] = { acc[t4][0], acc[t4][1], acc[t4][2], acc[t4][3] };
            xpose4(v, lane);
            unsigned short h[4], l[4];
#pragma unroll
            for (int rg = 0; rg < 4; ++rg) splitbf(v[rg], h[rg], l[rg]);
            rmH[t4] = make_ushort4(h[0], h[1], h[2], h[3]);
            rmL[t4] = make_ushort4(l[0], l[1], l[2], l[3]);
        }
    }

    __syncthreads();   // all reads done before any write (in-place aliasing)

#pragma unroll
    for (int t4 = 0; t4 < 4; ++t4) {
        const int io = cmI(rbase, 16 * t4 + n16);
        *(ushort4*)(Oh + io) = cmH[t4];
        *(ushort4*)(Ol + io) = cmL[t4];
    }
    if (ORh) {
        const int rowp = rbase + (lane & 3);            // this lane's output row
        const int c4b  = 4 * ((lane >> 2) & 3);         // col base within t4 block
#pragma unroll
        for (int t4 = 0; t4 < 4; ++t4) {
            const int io = rmI(rowp, 16 * t4 + c4b);    // 4 consecutive cols -> b64
            *(ushort4*)(ORh + io) = rmH[t4];
            *(ushort4*)(ORl + io) = rmL[t4];
        }
    }
    __syncthreads();
}

__global__ __launch_bounds__(256, 4) void meg_expm_kernel(
    const float* __restrict__ Rg, const float* __restrict__ Gg,
    float* __restrict__ out)
{
    // 32 KiB LDS: rm pair (A-operand, row-major) + cm pair (B-operand, col-major).
    __shared__ __align__(16) unsigned short sm[16384];
    unsigned short* rmh = sm;              // row-major h
    unsigned short* rml = sm + 4096;       // row-major l
    unsigned short* cmh = sm + 8192;       // col-major h
    unsigned short* cml = sm + 12288;      // col-major l
    float* FBG = (float*)sm;               // fp32 G staging (over rm pair)
    float* FBA = (float*)(sm + 8192);      // fp32 A (over cm pair)
    float* wmax = (float*)sm;              // 4 per-wave norm maxima (over rm pair; G dead)

    const int t = threadIdx.x;
    const int wv = t >> 6, lane = t & 63;
    const int tx = t & 15, ty = t >> 4;
    const long long base = (long long)blockIdx.x * 4096;

    // ---- stage grad into FBG (coalesced float4) ----
#pragma unroll
    for (int i = 0; i < 4; ++i) {
        int idx = t + i * 256;
        int r = idx >> 4, cc = idx & 15;
        *(float4*)&FBG[swzF(r, cc)] = ((const float4*)(Gg + base))[idx];
    }
    __syncthreads();

    // ---- A = log(R) - ETA*(G - G^T) -> FBA (fp32, swizzled) ----
#pragma unroll
    for (int i = 0; i < 4; ++i) {
        int r = 4 * ty + i;
        float4 rv = *(const float4*)&Rg[base + r * 64 + 4 * tx];
        float4 gv = *(const float4*)&FBG[swzF(r, tx)];
        float gt[4];
#pragma unroll
        for (int j = 0; j < 4; ++j)
            gt[j] = FBG[swzF(4 * tx + j, r >> 2) + (r & 3)];   // G[c][r]
        float4 o;
        o.x = logf(rv.x) - ETA * (gv.x - gt[0]);
        o.y = logf(rv.y) - ETA * (gv.y - gt[1]);
        o.z = logf(rv.z) - ETA * (gv.z - gt[2]);
        o.w = logf(rv.w) - ETA * (gv.w - gt[3]);
        *(float4*)&FBA[swzF(r, tx)] = o;
    }
    __syncthreads();

    // ---- 1-norm: each wave sums 16 cols (4 lanes/col, 16 rows each) ----
    {
        int c = 16 * wv + (lane & 15);
        int rq = lane >> 4;
        float cs = 0.f;
#pragma unroll
        for (int rr = 0; rr < 16; ++rr) {
            int r = 16 * rq + rr;
            cs += fabsf(FBA[swzF(r, c >> 2) + (c & 3)]);
        }
        cs += __shfl_xor(cs, 16);
        cs += __shfl_xor(cs, 32);
        cs = fmaxf(cs, __shfl_xor(cs, 8));
        cs = fmaxf(cs, __shfl_xor(cs, 4));
        cs = fmaxf(cs, __shfl_xor(cs, 2));
        cs = fmaxf(cs, __shfl_xor(cs, 1));
        if (lane == 0) wmax[wv] = cs;
    }
    __syncthreads();

    const float nrm = fmaxf(fmaxf(wmax[0], wmax[1]), fmaxf(wmax[2], wmax[3]));
    int s = 0;
    if (nrm > 1.0f) {
        s = (int)ceilf(log2f(nrm));
        if (s > 30) s = 30;
        if (s < 0) s = 0;
    }
    const float scale = exp2f(-(float)s);

    // ---- read A back, scale, split into Bm h/l (4x4 block at rows 4ty.., cols 4tx..) ----
    unsigned short abmh[4][4], abml[4][4];
#pragma unroll
    for (int i = 0; i < 4; ++i) {
        int r = 4 * ty + i;
        float4 a = *(const float4*)&FBA[swzF(r, tx)];
        float av[4] = { a.x, a.y, a.z, a.w };
#pragma unroll
        for (int j = 0; j < 4; ++j)
            splitbf(av[j] * scale, abmh[i][j], abml[i][j]);
    }
    __syncthreads();   // FBA/wmax reads done before overwrites below

    // ---- write Bm row-major (rm pair) and col-major (cm pair), all vectorized ----
#pragma unroll
    for (int i = 0; i < 4; ++i) {
        int r = 4 * ty + i;
        *(ushort4*)(rmh + rmI(r, 4 * tx)) = make_ushort4(abmh[i][0], abmh[i][1], abmh[i][2], abmh[i][3]);
        *(ushort4*)(rml + rmI(r, 4 * tx)) = make_ushort4(abml[i][0], abml[i][1], abml[i][2], abml[i][3]);
    }
#pragma unroll
    for (int j = 0; j < 4; ++j) {
        const int ic = cmI(4 * ty, 4 * tx + j);   // 4 consecutive rows, same chunk -> b64
        *(ushort4*)(cmh + ic) = make_ushort4(abmh[0][j], abmh[1][j], abmh[2][j], abmh[3][j]);
        *(ushort4*)(cml + ic) = make_ushort4(abml[0][j], abml[1][j], abml[2][j], abml[3][j]);
    }
    __syncthreads();

    // ---- gather Bm at this lane's C/D fragment positions into 16 regs ----
    const int n16 = lane & 15, q = lane >> 4;
    const int rbase = 16 * wv + 4 * q;
    float bmf[16];
#pragma unroll
    for (int t4 = 0; t4 < 4; ++t4) {
        const int ib = cmI(rbase, 16 * t4 + n16);
        const ushort4 hh = *(const ushort4*)(cmh + ib);
        const ushort4 ll = *(const ushort4*)(cml + ib);
        bmf[4 * t4 + 0] = bf2f(hh.x) + bf2f(ll.x);
        bmf[4 * t4 + 1] = bf2f(hh.y) + bf2f(ll.y);
        bmf[4 * t4 + 2] = bf2f(hh.z) + bf2f(ll.z);
        bmf[4 * t4 + 3] = bf2f(hh.w) + bf2f(ll.w);
    }

    // ---- M1: B2 = Bm*Bm -> rm (in-place); T0 = C9*Bm + C8*I -> cm (from regs) ----
    mmstage(rmh, rml, cmh, cml, cmh, cml, rmh, rml, nullptr, 0,
            bmf, C8, C9, true, wv, lane);

    // ---- Horner (B2 and T commute): T' = B2*T + cI*I + cB*Bm, cm in-place ----
    mmstage(rmh, rml, cmh, cml, cmh, cml, nullptr, nullptr, nullptr, 0,
            bmf, C6, C7, false, wv, lane);
    mmstage(rmh, rml, cmh, cml, cmh, cml, nullptr, nullptr, nullptr, 0,
            bmf, C4, C5, false, wv, lane);
    mmstage(rmh, rml, cmh, cml, cmh, cml, nullptr, nullptr, nullptr, 0,
            bmf, C2, C3, false, wv, lane);

    if (s == 0) {   // X0 is the answer: write fp32 directly to global
        mmstage(rmh, rml, cmh, cml, nullptr, nullptr, nullptr, nullptr, out, base,
                bmf, C0, C1, false, wv, lane);
        return;
    }
    // last Horner: X0 -> cm and rm (rm overwrites B2; mid-barrier guards)
    mmstage(rmh, rml, cmh, cml, cmh, cml, rmh, rml, nullptr, 0,
            bmf, C0, C1, false, wv, lane);

    // ---- s squarings: X <- X*X in-place; last writes fp32 to global ----
    for (int it = 0; it < s; ++it) {
        const bool last = (it == s - 1);
        mmstage(rmh, rml, cmh, cml, cmh, cml,
                last ? nullptr : rmh, last ? nullptr : rml,
                last ? out : nullptr, base,
                nullptr, 0.f, 0.f, false, wv, lane);
    }
}

extern "C" void kernel_launch(void* const* d_in, const int* in_sizes, int n_in,
                              void* d_out, int out_size, void* d_ws, size_t ws_size,
                              hipStream_t stream) {
    const float* R = (const float*)d_in[0];
    const float* G = (const float*)d_in[1];
    float* o = (float*)d_out;
    const int B = in_sizes[0] / (64 * 64);
    meg_expm_kernel<<<dim3(B), dim3(256), 0, stream>>>(R, G, o);
}